// Round 11
// baseline (2228.410 us; speedup 1.0000x reference)
//
#include <hip/hip_runtime.h>
#include <hip/hip_bf16.h>
#include <stdint.h>

#define M_DIM 8192
#define N_DIM 4096   // OUT_F
#define K_DIM 4096   // IN_F

#define BM 256
#define BN 256
#define BK 32
#define NT (K_DIM / BK)   // 128 K-tiles
#define NBUF 4

typedef __bf16 bf16_t;
typedef __attribute__((ext_vector_type(8))) __bf16 bf16x8;
typedef __attribute__((ext_vector_type(4))) float f32x4;

// ---------------- fp32 -> bf16 convert (vectorized, grid-stride) ----------------
__global__ void cvt_f32_to_bf16(const float* __restrict__ in, bf16_t* __restrict__ out, int n8) {
    int stride = gridDim.x * blockDim.x;
    for (int i = blockIdx.x * blockDim.x + threadIdx.x; i < n8; i += stride) {
        const float4* p = reinterpret_cast<const float4*>(in) + 2 * (size_t)i;
        float4 v0 = p[0];
        float4 v1 = p[1];
        bf16x8 o;
        o[0] = (bf16_t)v0.x; o[1] = (bf16_t)v0.y; o[2] = (bf16_t)v0.z; o[3] = (bf16_t)v0.w;
        o[4] = (bf16_t)v1.x; o[5] = (bf16_t)v1.y; o[6] = (bf16_t)v1.z; o[7] = (bf16_t)v1.w;
        *(reinterpret_cast<bf16x8*>(out) + (size_t)i) = o;
    }
}

// ---------------- 256x256 bf16 GEMM: ANTI-PHASE wave groups ----------------
// A: [M][K] bf16 row-major; B: [N][K] bf16 row-major (weight = B^T layout);
// C = A*B^T + bias, fp32 out.
//
// Mechanism (m114): separate waves on one CU co-schedule different pipes at
// full rate. All prior schedules kept the 8 waves phase-locked -> LDS and
// MFMA pipes ALTERNATE (tile time = LDS + MFMA summed, observed 9x).
// Fix: waves 0-3 (wm=0) are reader-first {read tile T; MFMA tile T};
// waves 4-7 (wm=1) are MFMA-first {MFMA on carried regs; read-ahead tile T+1
// into the same regs}. Round-robin wave->SIMD puts one of each group per
// SIMD: one bursts ds_reads while the other bursts MFMAs, swapping mid-tile.
//
// Hazards -- ONE barrier + ONE counted vmcnt per tile (4-deep ring):
//   RAW: per-wave outstanding at tile-T top = 8 (its 4 loads for T+1 issued
//        body T-2, 4 for T+2 issued body T-1) -> vmcnt(4) drains exactly T+1;
//        barrier then publishes buf[T+1] (every wave drained its share) for
//        wm=1's read-ahead. buf[T] published one tile earlier.
//   WAR: stage(T+3), issued after barrier-T, writes buf[(T-1)&3]. Last
//        readers: wm=0 in body T-1, wm=1 in body T-2 (read-ahead max target
//        is buf[T]); their reads were consumed (lgkm) before reaching
//        barrier-T. Disjoint from all in-flight reads.
//   Tail: top-126 vmcnt(0) (drains stage 127, issued body 124); RA=0 at 127.

#define MF(a, b, c) __builtin_amdgcn_mfma_f32_16x16x32_bf16((a), (b), (c), 0, 0, 0)
#define LD8(p) (*reinterpret_cast<const bf16x8*>(p))

#define STAGE_A(T) {                                                                  \
    const int sb_ = (T) & 3; const size_t kof_ = (size_t)(T) * BK;                    \
    __builtin_amdgcn_global_load_lds(                                                 \
        (const __attribute__((address_space(1))) void*)(gA0 + kof_),                  \
        (__attribute__((address_space(3))) void*)(&Asm[sb_][dst0]), 16, 0, 0);        \
    __builtin_amdgcn_global_load_lds(                                                 \
        (const __attribute__((address_space(1))) void*)(gA1 + kof_),                  \
        (__attribute__((address_space(3))) void*)(&Asm[sb_][dst1]), 16, 0, 0);        \
}

#define STAGE_B(T) {                                                                  \
    const int sb_ = (T) & 3; const size_t kof_ = (size_t)(T) * BK;                    \
    __builtin_amdgcn_global_load_lds(                                                 \
        (const __attribute__((address_space(1))) void*)(gB0 + kof_),                  \
        (__attribute__((address_space(3))) void*)(&Bsm[sb_][dst0]), 16, 0, 0);        \
    __builtin_amdgcn_global_load_lds(                                                 \
        (const __attribute__((address_space(1))) void*)(gB1 + kof_),                  \
        (__attribute__((address_space(3))) void*)(&Bsm[sb_][dst1]), 16, 0, 0);        \
}

// 32 MFMA: acc[i][j] += Ai * Bj
#define MM32(A0,A1,A2,A3,A4,A5,A6,A7, B0,B1,B2,B3)                                    \
    acc[0][0]=MF(A0,B0,acc[0][0]); acc[0][1]=MF(A0,B1,acc[0][1]);                     \
    acc[0][2]=MF(A0,B2,acc[0][2]); acc[0][3]=MF(A0,B3,acc[0][3]);                     \
    acc[1][0]=MF(A1,B0,acc[1][0]); acc[1][1]=MF(A1,B1,acc[1][1]);                     \
    acc[1][2]=MF(A1,B2,acc[1][2]); acc[1][3]=MF(A1,B3,acc[1][3]);                     \
    acc[2][0]=MF(A2,B0,acc[2][0]); acc[2][1]=MF(A2,B1,acc[2][1]);                     \
    acc[2][2]=MF(A2,B2,acc[2][2]); acc[2][3]=MF(A2,B3,acc[2][3]);                     \
    acc[3][0]=MF(A3,B0,acc[3][0]); acc[3][1]=MF(A3,B1,acc[3][1]);                     \
    acc[3][2]=MF(A3,B2,acc[3][2]); acc[3][3]=MF(A3,B3,acc[3][3]);                     \
    acc[4][0]=MF(A4,B0,acc[4][0]); acc[4][1]=MF(A4,B1,acc[4][1]);                     \
    acc[4][2]=MF(A4,B2,acc[4][2]); acc[4][3]=MF(A4,B3,acc[4][3]);                     \
    acc[5][0]=MF(A5,B0,acc[5][0]); acc[5][1]=MF(A5,B1,acc[5][1]);                     \
    acc[5][2]=MF(A5,B2,acc[5][2]); acc[5][3]=MF(A5,B3,acc[5][3]);                     \
    acc[6][0]=MF(A6,B0,acc[6][0]); acc[6][1]=MF(A6,B1,acc[6][1]);                     \
    acc[6][2]=MF(A6,B2,acc[6][2]); acc[6][3]=MF(A6,B3,acc[6][3]);                     \
    acc[7][0]=MF(A7,B0,acc[7][0]); acc[7][1]=MF(A7,B1,acc[7][1]);                     \
    acc[7][2]=MF(A7,B2,acc[7][2]); acc[7][3]=MF(A7,B3,acc[7][3]);

#define TILE(T, STG, VMSTR, RA) do {                                                  \
    asm volatile(VMSTR ::: "memory");                                                 \
    __builtin_amdgcn_s_barrier();                                                     \
    if (STG) { STAGE_A((T) + 3); STAGE_B((T) + 3); }                                  \
    bf16_t* Al_ = &Asm[(T) & 3][0];                                                   \
    bf16_t* Bl_ = &Bsm[(T) & 3][0];                                                   \
    bf16_t* An_ = &Asm[((T) + 1) & 3][0];                                             \
    bf16_t* Bn_ = &Bsm[((T) + 1) & 3][0];                                             \
    if (wm == 0) {                                                                    \
        /* reader-first: read tile T, then MFMA tile T (dep-ordered) */               \
        bf16x8 a0_=LD8(Al_+oa0), a1_=LD8(Al_+oa1), a2_=LD8(Al_+oa2), a3_=LD8(Al_+oa3);\
        bf16x8 a4_=LD8(Al_+oa4), a5_=LD8(Al_+oa5), a6_=LD8(Al_+oa6), a7_=LD8(Al_+oa7);\
        bf16x8 b0_=LD8(Bl_+ob0), b1_=LD8(Bl_+ob1), b2_=LD8(Bl_+ob2), b3_=LD8(Bl_+ob3);\
        __builtin_amdgcn_s_setprio(1);                                                \
        MM32(a0_,a1_,a2_,a3_,a4_,a5_,a6_,a7_, b0_,b1_,b2_,b3_);                       \
        __builtin_amdgcn_s_setprio(0);                                                \
    } else {                                                                          \
        /* MFMA-first on carried regs, then read-ahead T+1 in place */                \
        __builtin_amdgcn_s_setprio(1);                                                \
        MM32(cA0,cA1,cA2,cA3,cA4,cA5,cA6,cA7, cB0,cB1,cB2,cB3);                       \
        __builtin_amdgcn_s_setprio(0);                                                \
        __builtin_amdgcn_sched_group_barrier(0x8, 32, 0);   /* MFMAs first */         \
        if (RA) {                                                                     \
            cA0=LD8(An_+oa0); cA1=LD8(An_+oa1); cA2=LD8(An_+oa2); cA3=LD8(An_+oa3);   \
            cA4=LD8(An_+oa4); cA5=LD8(An_+oa5); cA6=LD8(An_+oa6); cA7=LD8(An_+oa7);   \
            cB0=LD8(Bn_+ob0); cB1=LD8(Bn_+ob1); cB2=LD8(Bn_+ob2); cB3=LD8(Bn_+ob3);   \
            __builtin_amdgcn_sched_group_barrier(0x100, 12, 0); /* then reads */      \
        }                                                                             \
    }                                                                                 \
} while (0)

__global__ __launch_bounds__(512, 2) void gemm_bf16_ap(
        const bf16_t* __restrict__ A, const bf16_t* __restrict__ B,
        const float* __restrict__ bias, float* __restrict__ C) {

    __shared__ __align__(16) bf16_t Asm[NBUF][BM * BK];   // 4 x 16 KB
    __shared__ __align__(16) bf16_t Bsm[NBUF][BN * BK];   // 4 x 16 KB -> 128 KiB

    const int tid  = threadIdx.x;
    const int lane = tid & 63;
    const int wave = tid >> 6;        // 0..7
    const int wm   = wave >> 2;       // 0..1 : M half AND anti-phase group
    const int wn   = wave & 3;        // 0..3 : N quarter (64 cols)

    // XCD-aware swizzle (nwg = 512, divisible by 8 -> bijective)
    const int nwg = gridDim.x;
    const int cpx = nwg >> 3;
    const int swz = (blockIdx.x & 7) * cpx + (blockIdx.x >> 3);
    const int ntn = N_DIM / BN;       // 16
    const int brow = (swz / ntn) * BM;
    const int bcol = (swz % ntn) * BN;

    // ---- staging geometry (r2-proven): tile = 256 rows x 32 bf16 = 16KB =
    // 1024 x 16B slots; slot s holds (row = s>>2, chunk = (s&3)^((s>>3)&3)).
    const int slot0 = wave * 128 + lane;
    const int slot1 = slot0 + 64;
    const int r0 = slot0 >> 2, c0 = ((slot0 & 3) ^ ((slot0 >> 3) & 3)) << 3;
    const int r1 = slot1 >> 2, c1 = ((slot1 & 3) ^ ((slot1 >> 3) & 3)) << 3;
    const bf16_t* gA0 = A + (size_t)(brow + r0) * K_DIM + c0;
    const bf16_t* gA1 = A + (size_t)(brow + r1) * K_DIM + c1;
    const bf16_t* gB0 = B + (size_t)(bcol + r0) * K_DIM + c0;
    const bf16_t* gB1 = B + (size_t)(bcol + r1) * K_DIM + c1;
    const int dst0 = wave * 1024;     // elem offset (slot * 8)
    const int dst1 = dst0 + 512;

    // ---- ds_read fragment offsets (r2-proven, measured 0 bank conflicts)
    const int fr = lane & 15;
    const int cc = lane >> 4;         // k-chunk 0..3 (k = cc*8)
#define AOFF(p, mi) ({ int row_ = wm*128 + (p)*64 + (mi)*16 + fr; \
                       row_*32 + ((cc ^ ((row_ >> 1) & 3)) << 3); })
#define BOFF(ni)    ({ int row_ = wn*64 + (ni)*16 + fr; \
                       row_*32 + ((cc ^ ((row_ >> 1) & 3)) << 3); })
    const int oa0 = AOFF(0,0), oa1 = AOFF(0,1), oa2 = AOFF(0,2), oa3 = AOFF(0,3);
    const int oa4 = AOFF(1,0), oa5 = AOFF(1,1), oa6 = AOFF(1,2), oa7 = AOFF(1,3);
    const int ob0 = BOFF(0), ob1 = BOFF(1), ob2 = BOFF(2), ob3 = BOFF(3);

    f32x4 acc[8][4];
#pragma unroll
    for (int i = 0; i < 8; i++)
#pragma unroll
        for (int j = 0; j < 4; j++)
            acc[i][j] = (f32x4){0.f, 0.f, 0.f, 0.f};

    // ---- prologue: stage tiles 0,1,2 (12 loads/wave); drain tile 0 (leave 8)
    STAGE_A(0) STAGE_B(0)
    STAGE_A(1) STAGE_B(1)
    STAGE_A(2) STAGE_B(2)
    asm volatile("s_waitcnt vmcnt(8)" ::: "memory");
    __builtin_amdgcn_s_barrier();

    // carried frags init: tile 0 (all waves; only wm=1 consumes in-loop)
    bf16x8 cA0 = LD8(&Asm[0][0] + oa0), cA1 = LD8(&Asm[0][0] + oa1);
    bf16x8 cA2 = LD8(&Asm[0][0] + oa2), cA3 = LD8(&Asm[0][0] + oa3);
    bf16x8 cA4 = LD8(&Asm[0][0] + oa4), cA5 = LD8(&Asm[0][0] + oa5);
    bf16x8 cA6 = LD8(&Asm[0][0] + oa6), cA7 = LD8(&Asm[0][0] + oa7);
    bf16x8 cB0 = LD8(&Bsm[0][0] + ob0), cB1 = LD8(&Bsm[0][0] + ob1);
    bf16x8 cB2 = LD8(&Bsm[0][0] + ob2), cB3 = LD8(&Bsm[0][0] + ob3);

    // ---- main loop: 4-tile unroll (ring indices fold to immediates)
    for (int t = 0; t < 124; t += 4) {
        TILE(t + 0, 1, "s_waitcnt vmcnt(4)", 1);
        TILE(t + 1, 1, "s_waitcnt vmcnt(4)", 1);
        TILE(t + 2, 1, "s_waitcnt vmcnt(4)", 1);
        TILE(t + 3, 1, "s_waitcnt vmcnt(4)", 1);
    }
    TILE(124, 1, "s_waitcnt vmcnt(4)", 1);   // stages tile 127 (last)
    TILE(125, 0, "s_waitcnt vmcnt(4)", 1);
    TILE(126, 0, "s_waitcnt vmcnt(0)", 1);
    TILE(127, 0, "s_nop 0",            0);

    // ---- epilogue: C/D layout col = lane&15, row = (lane>>4)*4 + r
    const int cc0 = bcol + wn * 64 + (lane & 15);
    const int rr0 = brow + wm * 128 + (lane >> 4) * 4;

    float bv[4];
#pragma unroll
    for (int ni = 0; ni < 4; ni++) bv[ni] = bias[cc0 + ni * 16];

#pragma unroll
    for (int p = 0; p < 2; p++) {
#pragma unroll
        for (int i = 0; i < 4; i++) {
#pragma unroll
            for (int r = 0; r < 4; r++) {
                const size_t row = (size_t)(rr0 + p * 64 + i * 16 + r);
#pragma unroll
                for (int ni = 0; ni < 4; ni++) {
                    C[row * N_DIM + cc0 + ni * 16] = acc[p * 4 + i][ni][r] + bv[ni];
                }
            }
        }
    }
}

// ---------------- safety-net fallback (no workspace): plain fp32 dot ----------------
__global__ void gemm_fallback_f32(const float* __restrict__ A, const float* __restrict__ B,
                                  const float* __restrict__ bias, float* __restrict__ C) {
    int n = blockIdx.x * 16 + threadIdx.x;
    int m = blockIdx.y * 16 + threadIdx.y;
    if (m >= M_DIM || n >= N_DIM) return;
    const float4* a = reinterpret_cast<const float4*>(A + (size_t)m * K_DIM);
    const float4* b = reinterpret_cast<const float4*>(B + (size_t)n * K_DIM);
    float s = 0.f;
    for (int k = 0; k < K_DIM / 4; k++) {
        float4 x = a[k], y = b[k];
        s += x.x * y.x + x.y * y.y + x.z * y.z + x.w * y.w;
    }
    C[(size_t)m * N_DIM + n] = s + bias[n];
}

extern "C" void kernel_launch(void* const* d_in, const int* in_sizes, int n_in,
                              void* d_out, int out_size, void* d_ws, size_t ws_size,
                              hipStream_t stream) {
    const float* x    = (const float*)d_in[0];   // [M][K] fp32
    const float* w    = (const float*)d_in[1];   // [N][K] fp32 (B^T layout)
    const float* bias = (const float*)d_in[2];   // [N] fp32
    float* out = (float*)d_out;

    const size_t xb = (size_t)M_DIM * K_DIM * sizeof(bf16_t);   // 64 MB
    const size_t wb = (size_t)N_DIM * K_DIM * sizeof(bf16_t);   // 32 MB

    if (ws_size >= xb + wb) {
        bf16_t* xbf = (bf16_t*)d_ws;
        bf16_t* wbf = (bf16_t*)((char*)d_ws + xb);

        cvt_f32_to_bf16<<<2048, 256, 0, stream>>>(x, xbf, (M_DIM * K_DIM) / 8);
        cvt_f32_to_bf16<<<1024, 256, 0, stream>>>(w, wbf, (N_DIM * K_DIM) / 8);

        const int grid = (M_DIM / BM) * (N_DIM / BN);   // 32 * 16 = 512
        gemm_bf16_ap<<<grid, 512, 0, stream>>>(xbf, wbf, bias, out);
    } else {
        dim3 block(16, 16);
        dim3 grid(N_DIM / 16, M_DIM / 16);
        gemm_fallback_f32<<<grid, block, 0, stream>>>(x, w, bias, out);
    }
}

// Round 12
// 336.947 us; speedup vs baseline: 6.6135x; 6.6135x over previous
//
#include <hip/hip_runtime.h>
#include <hip/hip_bf16.h>
#include <stdint.h>

#define M_DIM 8192
#define N_DIM 4096   // OUT_F
#define K_DIM 4096   // IN_F

#define BM 256
#define BN 256
#define BK 32
#define NT (K_DIM / BK)   // 128 K-tiles, 64 spans of 2
#define NBUF 5            // 5-deep ring -> 160 KiB LDS (AITER precedent on gfx950)

typedef __bf16 bf16_t;
typedef __attribute__((ext_vector_type(8))) __bf16 bf16x8;
typedef __attribute__((ext_vector_type(4))) float f32x4;

// ---------------- fp32 -> bf16 convert (vectorized, grid-stride) ----------------
__global__ void cvt_f32_to_bf16(const float* __restrict__ in, bf16_t* __restrict__ out, int n8) {
    int stride = gridDim.x * blockDim.x;
    for (int i = blockIdx.x * blockDim.x + threadIdx.x; i < n8; i += stride) {
        const float4* p = reinterpret_cast<const float4*>(in) + 2 * (size_t)i;
        float4 v0 = p[0];
        float4 v1 = p[1];
        bf16x8 o;
        o[0] = (bf16_t)v0.x; o[1] = (bf16_t)v0.y; o[2] = (bf16_t)v0.z; o[3] = (bf16_t)v0.w;
        o[4] = (bf16_t)v1.x; o[5] = (bf16_t)v1.y; o[6] = (bf16_t)v1.z; o[7] = (bf16_t)v1.w;
        *(reinterpret_cast<bf16x8*>(out) + (size_t)i) = o;
    }
}

// ---------------- 256x256 bf16 GEMM: WAR-pinned read/MFMA interleave ----------------
// A: [M][K] bf16 row-major; B: [N][K] bf16 row-major (weight = B^T layout);
// C = A*B^T + bias, fp32 out.
//
// Mechanism: per-CU tile time has been LDS(1152cyc) + MFMA(1242cyc) SUMMED in
// all 10 prior variants because reads and MFMAs are bunched and barriers keep
// all waves in the same bunch. Here every wave's instruction stream is
// {4 MFMA ; 1 ds_read} x12 ..., with each in-place A-frag reload pinned AFTER
// its row's MFMAs by a true WAR dependency (cannot be hoisted into a bunch
// without +32 VGPR, which pressure-aware scheduling avoids at 252/256 regs).
// The LDS pipe is fed during matrix-pipe busy time -> time ~ max, not sum.
//
// Schedule: spans of 2 tiles; ONE vmcnt(0) + ONE barrier per span (loads
// waited on were issued ~2 tiles (~4600 cyc) earlier -> queue empty, wait
// free). Full read-ahead: ALL of buf[X] is read during tile X-1's body
// (A frags reloaded in place, B frags parity-carried bE/bO).
//
// Hazards (5-ring, slots = tile % 5):
//  RAW: span s reads buf[2s+1] (tile-E body) and buf[2s+2] (tile-O body);
//       both staged at span s-1's top, drained by span s-1's vmcnt(0),
//       published by its barrier.
//  WAR: span s's stages write slots (2s+3)%5 and (2s+4)%5 = slots of tiles
//       2s-2 and 2s-1. buf[2s-2] reads were issued in tile 2s-3 and CONSUMED
//       (lgkm-drained) in tile 2s-2's body (span s-1); buf[2s-1] consumed in
//       tile 2s-1's body (span s-1). Span s-1's end barrier separates both
//       from the stages. Intra-span drift only touches disjoint slots.
//  Tail: span 62 stages tile 127 only; span 63 stages nothing; tile 127
//       runs MFMA-only (no RA).

#define MF(a, b, c) __builtin_amdgcn_mfma_f32_16x16x32_bf16((a), (b), (c), 0, 0, 0)
#define LD8(p) (*reinterpret_cast<const bf16x8*>(p))
#define GLL(src, dst) __builtin_amdgcn_global_load_lds(                               \
    (const __attribute__((address_space(1))) void*)(src),                             \
    (__attribute__((address_space(3))) void*)(dst), 16, 0, 0)
#define WR5(x) ((x) >= 5 ? (x) - 5 : (x))

#define STAGE_A(T, SL) { const size_t kof_ = (size_t)(T) * BK;                        \
    GLL(gA0 + kof_, &Asm[SL][dst0]); GLL(gA1 + kof_, &Asm[SL][dst1]); }
#define STAGE_B(T, SL) { const size_t kof_ = (size_t)(T) * BK;                        \
    GLL(gB0 + kof_, &Bsm[SL][dst0]); GLL(gB1 + kof_, &Bsm[SL][dst1]); }

// one row: 4 MFMA on frag aI, then WAR-pinned in-place reload of aI from next buf
#define ROW_RA(I, BC0,BC1,BC2,BC3)                                                    \
    acc[I][0]=MF(a##I,BC0,acc[I][0]); acc[I][1]=MF(a##I,BC1,acc[I][1]);               \
    acc[I][2]=MF(a##I,BC2,acc[I][2]); acc[I][3]=MF(a##I,BC3,acc[I][3]);               \
    a##I = LD8(An_ + oa##I);

#define ROW_NO(I, BC0,BC1,BC2,BC3)                                                    \
    acc[I][0]=MF(a##I,BC0,acc[I][0]); acc[I][1]=MF(a##I,BC1,acc[I][1]);               \
    acc[I][2]=MF(a##I,BC2,acc[I][2]); acc[I][3]=MF(a##I,BC3,acc[I][3]);

// tile body with read-ahead from slot NXSL (holds tile T+1)
#define TILE_RA(NXSL, BC0,BC1,BC2,BC3, BN0,BN1,BN2,BN3) {                             \
    bf16_t* An_ = &Asm[NXSL][0];                                                      \
    bf16_t* Bn_ = &Bsm[NXSL][0];                                                      \
    BN0 = LD8(Bn_ + ob0); BN1 = LD8(Bn_ + ob1);                                       \
    BN2 = LD8(Bn_ + ob2); BN3 = LD8(Bn_ + ob3);                                       \
    ROW_RA(0, BC0,BC1,BC2,BC3)                                                        \
    ROW_RA(1, BC0,BC1,BC2,BC3)                                                        \
    ROW_RA(2, BC0,BC1,BC2,BC3)                                                        \
    ROW_RA(3, BC0,BC1,BC2,BC3)                                                        \
    ROW_RA(4, BC0,BC1,BC2,BC3)                                                        \
    ROW_RA(5, BC0,BC1,BC2,BC3)                                                        \
    ROW_RA(6, BC0,BC1,BC2,BC3)                                                        \
    ROW_RA(7, BC0,BC1,BC2,BC3)                                                        \
}

#define TILE_LAST(BC0,BC1,BC2,BC3) {                                                  \
    ROW_NO(0, BC0,BC1,BC2,BC3)                                                        \
    ROW_NO(1, BC0,BC1,BC2,BC3)                                                        \
    ROW_NO(2, BC0,BC1,BC2,BC3)                                                        \
    ROW_NO(3, BC0,BC1,BC2,BC3)                                                        \
    ROW_NO(4, BC0,BC1,BC2,BC3)                                                        \
    ROW_NO(5, BC0,BC1,BC2,BC3)                                                        \
    ROW_NO(6, BC0,BC1,BC2,BC3)                                                        \
    ROW_NO(7, BC0,BC1,BC2,BC3)                                                        \
}

__global__ __launch_bounds__(512, 2) void gemm_bf16_ilv(
        const bf16_t* __restrict__ A, const bf16_t* __restrict__ B,
        const float* __restrict__ bias, float* __restrict__ C) {

    __shared__ __align__(16) bf16_t Asm[NBUF][BM * BK];   // 5 x 16 KB
    __shared__ __align__(16) bf16_t Bsm[NBUF][BN * BK];   // 5 x 16 KB -> 160 KiB

    const int tid  = threadIdx.x;
    const int lane = tid & 63;
    const int wave = tid >> 6;        // 0..7
    const int wm   = wave >> 2;       // 0..1 : M half (128 rows)
    const int wn   = wave & 3;        // 0..3 : N quarter (64 cols)

    // XCD-aware swizzle (nwg = 512, divisible by 8 -> bijective)
    const int nwg = gridDim.x;
    const int cpx = nwg >> 3;
    const int swz = (blockIdx.x & 7) * cpx + (blockIdx.x >> 3);
    const int ntn = N_DIM / BN;       // 16
    const int brow = (swz / ntn) * BM;
    const int bcol = (swz % ntn) * BN;

    // ---- staging geometry (r2-proven): tile = 256 rows x 32 bf16 = 16KB =
    // 1024 x 16B slots; slot s holds (row = s>>2, chunk = (s&3)^((s>>3)&3)).
    const int slot0 = wave * 128 + lane;
    const int slot1 = slot0 + 64;
    const int r0 = slot0 >> 2, c0 = ((slot0 & 3) ^ ((slot0 >> 3) & 3)) << 3;
    const int r1 = slot1 >> 2, c1 = ((slot1 & 3) ^ ((slot1 >> 3) & 3)) << 3;
    const bf16_t* gA0 = A + (size_t)(brow + r0) * K_DIM + c0;
    const bf16_t* gA1 = A + (size_t)(brow + r1) * K_DIM + c1;
    const bf16_t* gB0 = B + (size_t)(bcol + r0) * K_DIM + c0;
    const bf16_t* gB1 = B + (size_t)(bcol + r1) * K_DIM + c1;
    const int dst0 = wave * 1024;     // elem offset (slot * 8)
    const int dst1 = dst0 + 512;

    // ---- ds_read fragment offsets (r2-proven, measured 0 bank conflicts)
    const int fr = lane & 15;
    const int cc = lane >> 4;         // k-chunk 0..3 (k = cc*8)
#define AOFF(p, mi) ({ int row_ = wm*128 + (p)*64 + (mi)*16 + fr; \
                       row_*32 + ((cc ^ ((row_ >> 1) & 3)) << 3); })
#define BOFF(ni)    ({ int row_ = wn*64 + (ni)*16 + fr; \
                       row_*32 + ((cc ^ ((row_ >> 1) & 3)) << 3); })
    const int oa0 = AOFF(0,0), oa1 = AOFF(0,1), oa2 = AOFF(0,2), oa3 = AOFF(0,3);
    const int oa4 = AOFF(1,0), oa5 = AOFF(1,1), oa6 = AOFF(1,2), oa7 = AOFF(1,3);
    const int ob0 = BOFF(0), ob1 = BOFF(1), ob2 = BOFF(2), ob3 = BOFF(3);

    f32x4 acc[8][4];
#pragma unroll
    for (int i = 0; i < 8; i++)
#pragma unroll
        for (int j = 0; j < 4; j++)
            acc[i][j] = (f32x4){0.f, 0.f, 0.f, 0.f};

    // ---- prologue: stage tiles 0,1,2 (slots 0,1,2); drain; read tile-0 frags
    STAGE_A(0, 0) STAGE_B(0, 0)
    STAGE_A(1, 1) STAGE_B(1, 1)
    STAGE_A(2, 2) STAGE_B(2, 2)
    asm volatile("s_waitcnt vmcnt(0)" ::: "memory");
    __builtin_amdgcn_s_barrier();

    bf16x8 a0 = LD8(&Asm[0][0] + oa0), a1 = LD8(&Asm[0][0] + oa1);
    bf16x8 a2 = LD8(&Asm[0][0] + oa2), a3 = LD8(&Asm[0][0] + oa3);
    bf16x8 a4 = LD8(&Asm[0][0] + oa4), a5 = LD8(&Asm[0][0] + oa5);
    bf16x8 a6 = LD8(&Asm[0][0] + oa6), a7 = LD8(&Asm[0][0] + oa7);
    bf16x8 bE0 = LD8(&Bsm[0][0] + ob0), bE1 = LD8(&Bsm[0][0] + ob1);
    bf16x8 bE2 = LD8(&Bsm[0][0] + ob2), bE3 = LD8(&Bsm[0][0] + ob3);
    bf16x8 bO0 = bE0, bO1 = bE1, bO2 = bE2, bO3 = bE3;   // defined init
    asm volatile("s_waitcnt lgkmcnt(0)" ::: "memory");
    __builtin_amdgcn_s_barrier();     // prologue reads drained before any stage below

    // ---- main loop: 64 spans of 2 tiles; 1 vmcnt(0) + 1 barrier per span
    int sl1 = 1;   // slot of tile 2s+1
    for (int s = 0; s < 64; ++s) {
        const int T1 = 2 * s + 3, T2 = 2 * s + 4;
        const int slT1 = WR5(sl1 + 2), slT2 = WR5(sl1 + 3);
        if (T1 < NT) { STAGE_A(T1, slT1); STAGE_B(T1, slT1); }
        if (T2 < NT) { STAGE_A(T2, slT2); STAGE_B(T2, slT2); }
        const int sl2 = WR5(sl1 + 1);
        if (s < 63) {
            TILE_RA(sl1, bE0,bE1,bE2,bE3, bO0,bO1,bO2,bO3);   // tile 2s
            TILE_RA(sl2, bO0,bO1,bO2,bO3, bE0,bE1,bE2,bE3);   // tile 2s+1
            asm volatile("s_waitcnt vmcnt(0)" ::: "memory");
            __builtin_amdgcn_s_barrier();
        } else {
            TILE_RA(sl1, bE0,bE1,bE2,bE3, bO0,bO1,bO2,bO3);   // tile 126 (RA <- buf 127)
            TILE_LAST(bO0,bO1,bO2,bO3);                        // tile 127
        }
        sl1 = WR5(sl1 + 2);
    }

    // ---- epilogue: C/D layout col = lane&15, row = (lane>>4)*4 + r
    const int cc0 = bcol + wn * 64 + (lane & 15);
    const int rr0 = brow + wm * 128 + (lane >> 4) * 4;

    float bv[4];
#pragma unroll
    for (int ni = 0; ni < 4; ni++) bv[ni] = bias[cc0 + ni * 16];

#pragma unroll
    for (int p = 0; p < 2; p++) {
#pragma unroll
        for (int i = 0; i < 4; i++) {
#pragma unroll
            for (int r = 0; r < 4; r++) {
                const size_t row = (size_t)(rr0 + p * 64 + i * 16 + r);
#pragma unroll
                for (int ni = 0; ni < 4; ni++) {
                    C[row * N_DIM + cc0 + ni * 16] = acc[p * 4 + i][ni][r] + bv[ni];
                }
            }
        }
    }
}

// ---------------- safety-net fallback (no workspace): plain fp32 dot ----------------
__global__ void gemm_fallback_f32(const float* __restrict__ A, const float* __restrict__ B,
                                  const float* __restrict__ bias, float* __restrict__ C) {
    int n = blockIdx.x * 16 + threadIdx.x;
    int m = blockIdx.y * 16 + threadIdx.y;
    if (m >= M_DIM || n >= N_DIM) return;
    const float4* a = reinterpret_cast<const float4*>(A + (size_t)m * K_DIM);
    const float4* b = reinterpret_cast<const float4*>(B + (size_t)n * K_DIM);
    float s = 0.f;
    for (int k = 0; k < K_DIM / 4; k++) {
        float4 x = a[k], y = b[k];
        s += x.x * y.x + x.y * y.y + x.z * y.z + x.w * y.w;
    }
    C[(size_t)m * N_DIM + n] = s + bias[n];
}

extern "C" void kernel_launch(void* const* d_in, const int* in_sizes, int n_in,
                              void* d_out, int out_size, void* d_ws, size_t ws_size,
                              hipStream_t stream) {
    const float* x    = (const float*)d_in[0];   // [M][K] fp32
    const float* w    = (const float*)d_in[1];   // [N][K] fp32 (B^T layout)
    const float* bias = (const float*)d_in[2];   // [N] fp32
    float* out = (float*)d_out;

    const size_t xb = (size_t)M_DIM * K_DIM * sizeof(bf16_t);   // 64 MB
    const size_t wb = (size_t)N_DIM * K_DIM * sizeof(bf16_t);   // 32 MB

    if (ws_size >= xb + wb) {
        bf16_t* xbf = (bf16_t*)d_ws;
        bf16_t* wbf = (bf16_t*)((char*)d_ws + xb);

        cvt_f32_to_bf16<<<2048, 256, 0, stream>>>(x, xbf, (M_DIM * K_DIM) / 8);
        cvt_f32_to_bf16<<<1024, 256, 0, stream>>>(w, wbf, (N_DIM * K_DIM) / 8);

        const int grid = (M_DIM / BM) * (N_DIM / BN);   // 32 * 16 = 512
        gemm_bf16_ilv<<<grid, 512, 0, stream>>>(xbf, wbf, bias, out);
    } else {
        dim3 block(16, 16);
        dim3 grid(N_DIM / 16, M_DIM / 16);
        gemm_fallback_f32<<<grid, block, 0, stream>>>(x, w, bias, out);
    }
}